// Round 3
// baseline (133.872 us; speedup 1.0000x reference)
//
#include <hip/hip_runtime.h>

typedef __attribute__((ext_vector_type(8))) short bf16x8;
typedef __attribute__((ext_vector_type(4))) float f32x4;

static __device__ __forceinline__ short f2bf(float f) {
    union { float f; unsigned u; } v; v.f = f;
    unsigned r = v.u + 0x7fffu + ((v.u >> 16) & 1u);
    return (short)(r >> 16);
}

// ---------------------------------------------------------------------------
// P: fused precompute.
//  blocks 0..63   : VT[c=(m23*8+r)][k2=(r02*64+n23)] bf16 (plain layout)
//  blocks 64..127 : TLT[p=(m01*8+r02)][n01] bf16
// ---------------------------------------------------------------------------
__global__ __launch_bounds__(256) void ht_pre(const float* __restrict__ factors,
                                              const float* __restrict__ cores,
                                              short* __restrict__ TLT,
                                              short* __restrict__ VT) {
    const int bid = blockIdx.x, t = threadIdx.x;
    if (bid < 64) {
        __shared__ float TRl[64][9];          // padded: stride 9 floats breaks bank aliasing
        const int m23 = bid;
        const int m2 = m23 >> 3, m3 = m23 & 7;
        {   // TR slice for this m23: TRl[n23][r24], 2 values per thread
            const int v = t * 2;
            const int n23 = v >> 3;
            const int r24 = v & 7;            // even
            const int n2 = n23 >> 3, n3 = n23 & 7;
            const float* f2p = factors + 1024 + n2 * 64 + m2 * 8;
            const float* f3p = factors + 1536 + n3 * 64 + m3 * 8;
            const float* c2p = cores + 1024;
            float s0 = 0.f, s1 = 0.f;
            #pragma unroll
            for (int r23 = 0; r23 < 8; ++r23) {
                float a = f2p[r23];
                #pragma unroll
                for (int r34 = 0; r34 < 8; ++r34) {
                    float wv = a * f3p[r34];
                    s0 += wv * c2p[r23 * 64 + r34 * 8 + r24];
                    s1 += wv * c2p[r23 * 64 + r34 * 8 + r24 + 1];
                }
            }
            TRl[n23][r24] = s0;
            TRl[n23][r24 + 1] = s1;
        }
        __syncthreads();
        {   // VT rows c = m23*8 + r ; thread covers 16 consecutive k2
            const int r = t >> 5, seg = t & 31;
            const int k2b = seg * 16;
            const int r02 = k2b >> 6;
            float c0v[8];
            #pragma unroll
            for (int r24 = 0; r24 < 8; ++r24)
                c0v[r24] = cores[r02 * 64 + r24 * 8 + r];
            short ov[16];
            #pragma unroll
            for (int j = 0; j < 16; ++j) {
                const int n23 = (k2b + j) & 63;
                float s = 0.f;
                #pragma unroll
                for (int r24 = 0; r24 < 8; ++r24)
                    s += TRl[n23][r24] * c0v[r24];
                ov[j] = f2bf(s);
            }
            short* dst = VT + (m23 * 8 + r) * 512 + k2b;
            *(bf16x8*)dst = *(bf16x8*)&ov[0];
            *(bf16x8*)(dst + 8) = *(bf16x8*)&ov[8];
        }
    } else {
        const int idx = ((bid - 64) * 256 + t) * 2;
        const int p = idx >> 6, n01 = idx & 63;   // n01 even
        const int n0 = n01 >> 3, n1 = n01 & 7;
        const int mm = p >> 3, r02 = p & 7;
        const int m0 = mm >> 3, m1 = mm & 7;
        const float* f0 = factors + n0 * 64 + m0 * 8;
        const float* f1a = factors + 512 + n1 * 64 + m1 * 8;
        const float* f1b = f1a + 64;              // n1+1
        const float* c1 = cores + 512;
        float s0 = 0.f, s1 = 0.f;
        #pragma unroll
        for (int r01 = 0; r01 < 8; ++r01) {
            float a = f0[r01];
            #pragma unroll
            for (int r12 = 0; r12 < 8; ++r12) {
                float cv = c1[r01 * 64 + r12 * 8 + r02];
                s0 += a * f1a[r12] * cv;
                s1 += a * f1b[r12] * cv;
            }
        }
        unsigned w0 = (unsigned short)f2bf(s0);
        unsigned w1 = (unsigned short)f2bf(s1);
        *(unsigned*)&TLT[p * 64 + n01] = w0 | (w1 << 16);
    }
}

// ---------------------------------------------------------------------------
// G1: per-batch GEMM1.  A_b[m01][k2] = Y_b, written bf16 to ws, XOR-swizzled:
// 8-short granule index low-3-bits ^= (row & 7), so G2 can stage linearly.
// ---------------------------------------------------------------------------
__global__ __launch_bounds__(256, 2) void ht_g1(const float* __restrict__ x,
                                                const short* __restrict__ TLT,
                                                short* __restrict__ A) {
    __shared__ short XT[64 * 64];    // [n23][n01] swizzled, 8 KB
    __shared__ short YL[64 * 512];   // A_b swizzled image, 64 KB

    const int t = threadIdx.x;
    const int b = blockIdx.x;
    const int w = t >> 6;
    const int l = t & 63;
    const int lr = l & 15;
    const int lk = l >> 4;

    // phase 1: load x_b, bf16-convert, transpose into XT
    {
        const float* xb = x + b * 4096;
        #pragma unroll
        for (int j = 0; j < 4; ++j) {
            f32x4 v = *(const f32x4*)(xb + j * 1024 + t * 4);
            int n01 = j * 16 + (t >> 4);
            int rbase = (t & 15) * 4;
            #pragma unroll
            for (int e = 0; e < 4; ++e) {
                int rr = rbase + e;
                XT[rr * 64 + (n01 ^ ((rr & 7) << 3))] = f2bf(v[e]);
            }
        }
    }
    __syncthreads();

    // phase 2: Y[p=512][n23=64] = TLT[p][n01] * X[n01][n23] -> YL (=A_b swizzled)
    {
        bf16x8 bx[4][2];
        #pragma unroll
        for (int ct = 0; ct < 4; ++ct)
            #pragma unroll
            for (int kb = 0; kb < 2; ++kb) {
                int rr = ct * 16 + lr;
                int cc = kb * 32 + lk * 8;
                bx[ct][kb] = *(const bf16x8*)&XT[rr * 64 + (cc ^ ((rr & 7) << 3))];
            }
        #pragma unroll
        for (int pt = 0; pt < 8; ++pt) {
            int pbase = w * 128 + pt * 16;
            const short* arow = TLT + (pbase + lr) * 64;
            bf16x8 a0 = *(const bf16x8*)&arow[lk * 8];
            bf16x8 a1 = *(const bf16x8*)&arow[32 + lk * 8];
            #pragma unroll
            for (int ct = 0; ct < 4; ++ct) {
                f32x4 acc = {0.f, 0.f, 0.f, 0.f};
                acc = __builtin_amdgcn_mfma_f32_16x16x32_bf16(a0, bx[ct][0], acc, 0, 0, 0);
                acc = __builtin_amdgcn_mfma_f32_16x16x32_bf16(a1, bx[ct][1], acc, 0, 0, 0);
                #pragma unroll
                for (int reg = 0; reg < 4; ++reg) {
                    int p = pbase + lk * 4 + reg;
                    int m = p >> 3;                        // A row (within batch)
                    int c2 = (p & 7) * 64 + ct * 16 + lr;  // k2
                    YL[m * 512 + (c2 ^ ((m & 7) << 3))] = f2bf(acc[reg]);
                }
            }
        }
    }
    __syncthreads();

    // phase 3: coalesced copy YL -> A (keeps swizzled layout)
    {
        short* Ab = A + b * 32768;
        #pragma unroll
        for (int it = 0; it < 16; ++it) {
            int chunk = it * 256 + t;
            *(bf16x8*)(Ab + chunk * 8) = *(const bf16x8*)(YL + chunk * 8);
        }
    }
}

// ---------------------------------------------------------------------------
// G2: C[32768][512] = A[32768][512] * V[512][512]   (A swizzled bf16, VT=B^T)
// 128x128 tiles, BK=64, dbuf LDS A-stage via global_load_lds, 4 blocks/CU.
// ---------------------------------------------------------------------------
__global__ __launch_bounds__(256, 4) void ht_g2(const short* __restrict__ A,
                                                const short* __restrict__ VT,
                                                float* __restrict__ out) {
    __shared__ short As[2][128 * 64];   // 2 x 16 KB

    const int t = threadIdx.x;
    const int bid = blockIdx.x;
    const int rt = bid >> 2;            // 256 row tiles
    const int ct = bid & 3;             // 4 col tiles
    const int w = t >> 6, l = t & 63;
    const int lr = l & 15, lk = l >> 4;
    const int wm = w >> 1, wn = w & 1;

    const short* Ab = A + rt * 65536;   // 128 rows x 512
    const int cbase = ct * 128 + wn * 64;

    f32x4 acc[4][4];
    #pragma unroll
    for (int rf = 0; rf < 4; ++rf)
        #pragma unroll
        for (int cf = 0; cf < 4; ++cf)
            acc[rf][cf] = (f32x4){0.f, 0.f, 0.f, 0.f};

    auto stage = [&](int buf, int kb) {
        #pragma unroll
        for (int q = 0; q < 4; ++q) {
            int chunk = q * 256 + t;
            int row = chunk >> 3, blk = chunk & 7;
            const short* src = Ab + row * 512 + kb * 64 + blk * 8;
            __builtin_amdgcn_global_load_lds(
                (const __attribute__((address_space(1))) unsigned int*)src,
                (__attribute__((address_space(3))) unsigned int*)&As[buf][chunk * 8],
                16, 0, 0);
        }
    };

    stage(0, 0);
    __syncthreads();

    for (int kb = 0; kb < 8; ++kb) {
        const int cur = kb & 1;
        if (kb < 7) stage(cur ^ 1, kb + 1);
        #pragma unroll
        for (int kh = 0; kh < 2; ++kh) {
            bf16x8 bfr[4];
            #pragma unroll
            for (int cf = 0; cf < 4; ++cf)
                bfr[cf] = *(const bf16x8*)&VT[(cbase + cf * 16 + lr) * 512 + kb * 64 + kh * 32 + lk * 8];
            #pragma unroll
            for (int rf = 0; rf < 4; ++rf) {
                int row = wm * 64 + rf * 16 + lr;
                int blk = (kh * 4 + lk) ^ (row & 7);
                bf16x8 af = *(const bf16x8*)&As[cur][row * 64 + blk * 8];
                #pragma unroll
                for (int cf = 0; cf < 4; ++cf)
                    acc[rf][cf] = __builtin_amdgcn_mfma_f32_16x16x32_bf16(af, bfr[cf], acc[rf][cf], 0, 0, 0);
            }
        }
        __syncthreads();
    }

    float* ob = out + (rt * 128 + wm * 64) * 512 + ct * 128 + wn * 64;
    #pragma unroll
    for (int rf = 0; rf < 4; ++rf)
        #pragma unroll
        for (int cf = 0; cf < 4; ++cf)
            #pragma unroll
            for (int reg = 0; reg < 4; ++reg)
                __builtin_nontemporal_store(acc[rf][cf][reg],
                                            &ob[(rf * 16 + lk * 4 + reg) * 512 + cf * 16 + lr]);
}

extern "C" void kernel_launch(void* const* d_in, const int* in_sizes, int n_in,
                              void* d_out, int out_size, void* d_ws, size_t ws_size,
                              hipStream_t stream) {
    const float* x       = (const float*)d_in[0];   // (512,8,8,8,8)
    const float* factors = (const float*)d_in[1];   // (4,8,8,8)
    const float* cores   = (const float*)d_in[2];   // (3,8,8,8)
    float* out = (float*)d_out;                     // (512,8,8,8,8,8)

    short* TLT = (short*)d_ws;           // 32768  bf16 (64 KB)
    short* VT  = TLT + 32768;            // 262144 bf16 (512 KB)
    short* A   = VT + 262144;            // 16.78M bf16 (32 MB), swizzled

    hipLaunchKernelGGL(ht_pre, dim3(128), dim3(256), 0, stream, factors, cores, TLT, VT);
    hipLaunchKernelGGL(ht_g1, dim3(512), dim3(256), 0, stream, x, TLT, A);
    hipLaunchKernelGGL(ht_g2, dim3(1024), dim3(256), 0, stream, A, VT, out);
}